// Round 2
// baseline (615.580 us; speedup 1.0000x reference)
//
#include <hip/hip_runtime.h>

// y[n,m,:] = x[n,m,:] @ W[l(m)] * (1/sqrt(128))
// x: [100000, 16, 128] f32   W: [4, 128, 128] f32   y: [100000, 16, 128] f32
//
// R1 post-mortem: latency-bound at 2.4 TB/s (30% HBM), VGPR squeezed to 64 so
// the compiler serialized the x-loads. R2: per-wave tile 16 rows x 128 cols
// (acc[8] = 32 AGPR), all 8 independent x-loads issued up-front into a
// register buffer (8 outstanding 16B loads/wave), native bf16 cvt.
// __launch_bounds__(256,4) pins 4 waves/SIMD (<=128 unified regs).
//
// MFMA operand note: A and B fragments use the SAME k->(lanegroup,elem)
// mapping, so the result is invariant to the instruction's internal K
// permutation. C/D layout: col=lane&15, row=(lane>>4)*4+reg (verified R1).

typedef __bf16 bf16x8 __attribute__((ext_vector_type(8)));
typedef float f32x4 __attribute__((ext_vector_type(4)));
typedef unsigned short u16x8 __attribute__((ext_vector_type(8)));

#define N_NODES 100000
#define MCOMP 16
#define CIN 128
#define ROWSTRIDE (MCOMP * CIN)  // 2048 floats per node

// round-to-nearest-even f32 -> bf16 bits (for weight prep)
__device__ __forceinline__ unsigned short f2b(float f) {
    unsigned int u = __float_as_uint(f);
    unsigned int r = (u + 0x7fffu + ((u >> 16) & 1u)) >> 16;
    return (unsigned short)r;
}

// Wt[l][d][c] = W[l][c][d] * (1/sqrt(128)) as bf16 bits. 4*128*128*2B = 128KiB.
__global__ void prep_weights(const float* __restrict__ w,
                             unsigned short* __restrict__ wt) {
    int idx = blockIdx.x * blockDim.x + threadIdx.x;  // 0..65535
    int l = idx >> 14;
    int rem = idx & 16383;
    int d = rem >> 7;
    int c = rem & 127;
    const float pw = 0.08838834764831845f;  // 1/sqrt(128)
    float v = w[(l << 14) + (c << 7) + d] * pw;
    wt[idx] = f2b(v);
}

__global__ __launch_bounds__(256, 4) void linear_mfma(
        const float* __restrict__ x,
        const unsigned short* __restrict__ wt,
        float* __restrict__ y) {
    const int m = blockIdx.y;
    const int l = (m >= 9) ? 3 : (m >= 4) ? 2 : (m >= 1) ? 1 : 0;
    const int nbase = blockIdx.x * 64;
    const int wid = threadIdx.x >> 6;
    const int lane = threadIdx.x & 63;
    const int lr = lane & 15;   // A row-in-frag / B col / D col
    const int lk = lane >> 4;   // k lane-group

    const unsigned short* wl = wt + (l << 14);

    // this wave: 16 rows [nbase + wid*16, +16)
    int row = nbase + wid * 16 + lr;
    int rc = row < N_NODES ? row : N_NODES - 1;  // clamp loads in tail tile
    const float* xa = x + (size_t)rc * ROWSTRIDE + m * CIN + lk * 8;

    // ---- phase 1: issue ALL x loads (8 independent global_load_dwordx4) ----
    f32x4 af[8];
#pragma unroll
    for (int kk = 0; kk < 4; ++kk) {
        af[2 * kk]     = *reinterpret_cast<const f32x4*>(xa + kk * 32);
        af[2 * kk + 1] = *reinterpret_cast<const f32x4*>(xa + kk * 32 + 4);
    }

    // ---- phase 2: convert to 4 bf16x8 A fragments ----
    bf16x8 a[4];
#pragma unroll
    for (int kk = 0; kk < 4; ++kk) {
        bf16x8 t;
#pragma unroll
        for (int j = 0; j < 4; ++j) {
            t[j]     = (__bf16)af[2 * kk][j];
            t[j + 4] = (__bf16)af[2 * kk + 1][j];
        }
        a[kk] = t;
    }

    // ---- phase 3: MFMA over K, B fragments streamed from L1 ----
    f32x4 acc[8];
#pragma unroll
    for (int nn = 0; nn < 8; ++nn) acc[nn] = (f32x4){0.f, 0.f, 0.f, 0.f};

#pragma unroll
    for (int kk = 0; kk < 4; ++kk) {
#pragma unroll
        for (int nn = 0; nn < 8; ++nn) {
            // lane reads Wt[l][nn*16 + lr][kk*32 + lk*8 .. +8] (16B, L1-hot)
            u16x8 br = *reinterpret_cast<const u16x8*>(
                wl + (((nn * 16 + lr) << 7) + kk * 32 + lk * 8));
            bf16x8 b = __builtin_bit_cast(bf16x8, br);
            acc[nn] = __builtin_amdgcn_mfma_f32_16x16x32_bf16(a[kk], b, acc[nn], 0, 0, 0);
        }
    }

    // ---- epilogue: D col = lane&15, row = (lane>>4)*4 + reg ----
    int rbase = nbase + wid * 16 + lk * 4;
#pragma unroll
    for (int r = 0; r < 4; ++r) {
        int rowq = rbase + r;
        if (rowq < N_NODES) {
            float* yp = y + (size_t)rowq * ROWSTRIDE + m * CIN + lr;
#pragma unroll
            for (int nn = 0; nn < 8; ++nn)
                yp[nn * 16] = acc[nn][r];
        }
    }
}

extern "C" void kernel_launch(void* const* d_in, const int* in_sizes, int n_in,
                              void* d_out, int out_size, void* d_ws, size_t ws_size,
                              hipStream_t stream) {
    const float* x = (const float*)d_in[0];
    const float* w = (const float*)d_in[1];
    float* y = (float*)d_out;
    unsigned short* wt = (unsigned short*)d_ws;  // 128 KiB of scratch used

    prep_weights<<<256, 256, 0, stream>>>(w, wt);

    dim3 grid((N_NODES + 63) / 64, MCOMP);  // 1563 x 16
    linear_mfma<<<grid, 256, 0, stream>>>(x, wt, y);
}

// Round 3
// 534.281 us; speedup vs baseline: 1.1522x; 1.1522x over previous
//
#include <hip/hip_runtime.h>

// y[n,m,:] = x[n,m,:] @ W[l(m)] * (1/sqrt(128))
// x: [100000, 16, 128] f32   W: [4, 128, 128] f32   y: [100000, 16, 128] f32
//
// R2 post-mortem: W-fragment global loads sat on the MFMA critical path
// (L1/L2 latency per MFMA, compiler held few in flight). R3: W is fully
// REGISTER-resident (each wave owns a 32-wide d-slice -> 8 frags = 32 VGPR,
// loaded once). K-loop = x loads + MFMA only. Operands SWAPPED vs R1:
// D = Wt . x^T, so each lane's 4 acc elems are 4 contiguous d values ->
// dwordx4 stores, single row<N guard. x double-buffered ping-pong (static
// indices). Cost: x read by all 4 waves of a block (L1/L2 dedups).
//
// MFMA mapping note: A(=Wt rows d) and B(=x cols n) fragments use the same
// k->(lanegroup,elem) mapping, so the internal K permutation cancels.
// C/D layout: col(lane&15)=n, row((lane>>4)*4+reg)=d  (HW-verified R1).

typedef __bf16 bf16x8 __attribute__((ext_vector_type(8)));
typedef float f32x4 __attribute__((ext_vector_type(4)));
typedef unsigned short u16x8 __attribute__((ext_vector_type(8)));

#define N_NODES 100000
#define MCOMP 16
#define CIN 128
#define ROWSTRIDE (MCOMP * CIN)  // 2048 floats per node

// round-to-nearest-even f32 -> bf16 bits (for weight prep)
__device__ __forceinline__ unsigned short f2b(float f) {
    unsigned int u = __float_as_uint(f);
    unsigned int r = (u + 0x7fffu + ((u >> 16) & 1u)) >> 16;
    return (unsigned short)r;
}

// Wt[l][d][c] = W[l][c][d] * (1/sqrt(128)) as bf16 bits. 4*128*128*2B = 128KiB.
__global__ void prep_weights(const float* __restrict__ w,
                             unsigned short* __restrict__ wt) {
    int idx = blockIdx.x * blockDim.x + threadIdx.x;  // 0..65535
    int l = idx >> 14;
    int rem = idx & 16383;
    int d = rem >> 7;
    int c = rem & 127;
    const float pw = 0.08838834764831845f;  // 1/sqrt(128)
    float v = w[(l << 14) + (c << 7) + d] * pw;
    wt[idx] = f2b(v);
}

__device__ __forceinline__ void load_tile(const float* __restrict__ base,
                                          f32x4 buf[8]) {
#pragma unroll
    for (int kk = 0; kk < 4; ++kk) {
        buf[2 * kk]     = *reinterpret_cast<const f32x4*>(base + kk * 32);
        buf[2 * kk + 1] = *reinterpret_cast<const f32x4*>(base + kk * 32 + 4);
    }
}

__device__ __forceinline__ void compute_tile(const f32x4 buf[8],
                                             const bf16x8 wf[2][4],
                                             float* __restrict__ yp,
                                             bool valid) {
    f32x4 acc0 = (f32x4){0.f, 0.f, 0.f, 0.f};
    f32x4 acc1 = (f32x4){0.f, 0.f, 0.f, 0.f};
#pragma unroll
    for (int kk = 0; kk < 4; ++kk) {
        bf16x8 xb;
#pragma unroll
        for (int j = 0; j < 4; ++j) {
            xb[j]     = (__bf16)buf[2 * kk][j];
            xb[j + 4] = (__bf16)buf[2 * kk + 1][j];
        }
        acc0 = __builtin_amdgcn_mfma_f32_16x16x32_bf16(wf[0][kk], xb, acc0, 0, 0, 0);
        acc1 = __builtin_amdgcn_mfma_f32_16x16x32_bf16(wf[1][kk], xb, acc1, 0, 0, 0);
    }
    if (valid) {
        *reinterpret_cast<f32x4*>(yp)      = acc0;
        *reinterpret_cast<f32x4*>(yp + 16) = acc1;
    }
}

__global__ __launch_bounds__(256, 4) void linear_mfma(
        const float* __restrict__ x,
        const unsigned short* __restrict__ wt,
        float* __restrict__ y) {
    const int m = blockIdx.y;
    const int l = (m >= 9) ? 3 : (m >= 4) ? 2 : (m >= 1) ? 1 : 0;
    const int wid = threadIdx.x >> 6;   // wave owns d-slice [wid*32, wid*32+32)
    const int lane = threadIdx.x & 63;
    const int lr = lane & 15;           // A row d-in-frag / B col n / D col n
    const int lk = lane >> 4;           // k lane-group

    // W fragments (A-operand), register-resident: d = wid*32+nn2*16+lr,
    // k = kk*32 + lk*8 .. +8
    const unsigned short* wl = wt + (l << 14);
    bf16x8 wf[2][4];
#pragma unroll
    for (int nn2 = 0; nn2 < 2; ++nn2)
#pragma unroll
        for (int kk = 0; kk < 4; ++kk)
            wf[nn2][kk] = __builtin_bit_cast(bf16x8, *reinterpret_cast<const u16x8*>(
                wl + (((wid * 32 + nn2 * 16 + lr) << 7) + kk * 32 + lk * 8)));

    const int nbase = blockIdx.x * 128;  // block covers 128 n-rows, 8 tiles of 16

    f32x4 bufA[8], bufB[8];
    if (nbase + 128 <= N_NODES) {
        // fast path: no clamping, ping-pong double buffer, static offsets
        const float* xp = x + (size_t)(nbase + lr) * ROWSTRIDE + m * CIN + lk * 8;
        float* yp = y + (size_t)(nbase + lr) * ROWSTRIDE + m * CIN + wid * 32 + lk * 4;
        const size_t step = (size_t)16 * ROWSTRIDE;

        load_tile(xp, bufA);
#pragma unroll
        for (int itp = 0; itp < 4; ++itp) {
            load_tile(xp + (size_t)(2 * itp + 1) * step, bufB);
            compute_tile(bufA, wf, yp + (size_t)(2 * itp) * step, true);
            if (itp < 3) load_tile(xp + (size_t)(2 * itp + 2) * step, bufA);
            compute_tile(bufB, wf, yp + (size_t)(2 * itp + 1) * step, true);
        }
    } else {
        // tail block: clamp loads, guard stores
#pragma unroll
        for (int it = 0; it < 8; ++it) {
            int row = nbase + it * 16 + lr;
            int rc = row < N_NODES ? row : N_NODES - 1;
            load_tile(x + (size_t)rc * ROWSTRIDE + m * CIN + lk * 8, bufA);
            compute_tile(bufA, wf,
                         y + (size_t)row * ROWSTRIDE + m * CIN + wid * 32 + lk * 4,
                         row < N_NODES);
        }
    }
}

extern "C" void kernel_launch(void* const* d_in, const int* in_sizes, int n_in,
                              void* d_out, int out_size, void* d_ws, size_t ws_size,
                              hipStream_t stream) {
    const float* x = (const float*)d_in[0];
    const float* w = (const float*)d_in[1];
    float* y = (float*)d_out;
    unsigned short* wt = (unsigned short*)d_ws;  // 128 KiB of scratch used

    prep_weights<<<256, 256, 0, stream>>>(w, wt);

    dim3 grid((N_NODES + 127) / 128, MCOMP);  // 782 x 16
    linear_mfma<<<grid, 256, 0, stream>>>(x, wt, y);
}

// Round 4
// 341.881 us; speedup vs baseline: 1.8006x; 1.5628x over previous
//
#include <hip/hip_runtime.h>

// y[n,m,:] = x[n,m,:] @ W[l(m)] * (1/sqrt(128))
// x: [100000, 16, 128] f32   W: [4, 128, 128] f32   y: [100000, 16, 128] f32
//
// R3 post-mortem: compiler refuses to hold a deep VGPR prefetch pipeline
// (VGPR=52, loads sunk next to uses, 2.2 TB/s). R4: catalog-minimum 2-phase
// pipeline with explicit global_load_lds (width 16) -- loads are
// fire-and-forget into LDS, so outstanding depth is decoupled from VGPRs.
// Two static 16KB half-buffers (32 rows x 512B), counted s_waitcnt vmcnt(4)
// + raw s_barrier per iter, sched_barrier(0) pins stage-issue order.
// LDS would be 16-way bank-conflicted (row stride 512B) -> rule #21:
// pre-swizzle the GLOBAL source (slot ^= row&7), linear DMA write, XOR on
// ds_read. W register-resident per wave (32 VGPR). 100000%32==0 -> no clamps.
//
// MFMA: A=W-frag(d), B=x-frag(n), same k->(lanegroup,elem) map both sides so
// the internal K permutation cancels. D: col(lane&15)=n, row((lane>>4)*4+reg)=d
// (HW-verified in R1-R3 epilogues).

typedef __bf16 bf16x8 __attribute__((ext_vector_type(8)));
typedef float f32x4 __attribute__((ext_vector_type(4)));
typedef unsigned short u16x8 __attribute__((ext_vector_type(8)));

#define N_NODES 100000
#define MCOMP 16
#define CIN 128
#define ROWSTRIDE (MCOMP * CIN)  // 2048 floats per node

__device__ __forceinline__ unsigned short f2b(float f) {
    unsigned int u = __float_as_uint(f);
    unsigned int r = (u + 0x7fffu + ((u >> 16) & 1u)) >> 16;
    return (unsigned short)r;
}

// Wt[l][d][c] = W[l][c][d] * (1/sqrt(128)) as bf16 bits. 128 KiB in d_ws.
__global__ void prep_weights(const float* __restrict__ w,
                             unsigned short* __restrict__ wt) {
    int idx = blockIdx.x * blockDim.x + threadIdx.x;  // 0..65535
    int l = idx >> 14;
    int rem = idx & 16383;
    int d = rem >> 7;
    int c = rem & 127;
    const float pw = 0.08838834764831845f;  // 1/sqrt(128)
    wt[idx] = f2b(w[(l << 14) + (c << 7) + d] * pw);
}

__global__ __launch_bounds__(256, 4) void linear_mfma(
        const float* __restrict__ x,
        const unsigned short* __restrict__ wt,
        float* __restrict__ y) {
    __shared__ float lds0[32 * 128];  // 16 KiB half-buffer A
    __shared__ float lds1[32 * 128];  // 16 KiB half-buffer B

    const int m = blockIdx.y;
    const int l = (m >= 9) ? 3 : (m >= 4) ? 2 : (m >= 1) ? 1 : 0;
    const int wid = threadIdx.x >> 6;
    const int lane = threadIdx.x & 63;
    const int lr = lane & 15;   // W-frag d-row / x-frag n / D col (n)
    const int lk = lane >> 4;   // k lane-group
    const int nbase = blockIdx.x * 128;

    // W fragments, register-resident: d = wid*32 + df*16 + lr, k = kk*32+lk*8..+8
    const unsigned short* wl = wt + (l << 14);
    bf16x8 wf[2][4];
#pragma unroll
    for (int df = 0; df < 2; ++df)
#pragma unroll
        for (int kk = 0; kk < 4; ++kk)
            wf[df][kk] = __builtin_bit_cast(bf16x8, *(const u16x8*)(
                wl + (((wid * 32 + df * 16 + lr) << 7) + kk * 32 + lk * 8)));

    // stage half h (rows nbase+h*32 .. +32) into buf: 4 global_load_lds/wave,
    // 1KB each, LDS linear; global source pre-swizzled slot^=(row&7).
    auto stage = [&](float* buf, int h) {
        const int hbase = nbase + h * 32;
#pragma unroll
        for (int j = 0; j < 4; ++j) {
            int seg = wid * 4 + j;                 // 1KB segment, wave-uniform
            int row = seg * 2 + (lane >> 5);       // 2 rows per segment
            int slot = (lane & 31) ^ (row & 7);    // 16B slot, pre-swizzled
            const float* src = x + (size_t)(hbase + row) * ROWSTRIDE
                               + m * CIN + slot * 4;
            __builtin_amdgcn_global_load_lds(
                (const __attribute__((address_space(1))) void*)src,
                (__attribute__((address_space(3))) void*)(buf + seg * 256),
                16, 0, 0);
        }
    };

    // compute half h from buf (ds_read XOR-deswizzled), MFMA, store to y.
    // Exactly 4 vmem stores per wave (counted in the vmcnt discipline).
    auto comp = [&](const float* buf, int h) {
        f32x4 acc[2][2];
#pragma unroll
        for (int rf = 0; rf < 2; ++rf)
#pragma unroll
            for (int df = 0; df < 2; ++df)
                acc[rf][df] = (f32x4){0.f, 0.f, 0.f, 0.f};

#pragma unroll
        for (int kk = 0; kk < 4; ++kk) {
#pragma unroll
            for (int rf = 0; rf < 2; ++rf) {
                int row = rf * 16 + lr;
                int sw = row & 7;
                const float* rbase = buf + row * 128 + kk * 32;
                f32x4 v0 = *(const f32x4*)(rbase + ((lk * 2) ^ sw) * 4);
                f32x4 v1 = *(const f32x4*)(rbase + ((lk * 2 + 1) ^ sw) * 4);
                bf16x8 xb;
#pragma unroll
                for (int jj = 0; jj < 4; ++jj) {
                    xb[jj] = (__bf16)v0[jj];
                    xb[jj + 4] = (__bf16)v1[jj];
                }
                acc[rf][0] = __builtin_amdgcn_mfma_f32_16x16x32_bf16(
                    wf[0][kk], xb, acc[rf][0], 0, 0, 0);
                acc[rf][1] = __builtin_amdgcn_mfma_f32_16x16x32_bf16(
                    wf[1][kk], xb, acc[rf][1], 0, 0, 0);
            }
        }
        const int hbase = nbase + h * 32;
#pragma unroll
        for (int rf = 0; rf < 2; ++rf)
#pragma unroll
            for (int df = 0; df < 2; ++df) {
                float* yp = y + (size_t)(hbase + rf * 16 + lr) * ROWSTRIDE
                            + m * CIN + wid * 32 + df * 16 + lk * 4;
                *(f32x4*)yp = acc[rf][df];
            }
    };

    if (nbase + 128 <= N_NODES) {
        // steady schedule: stage(t+1); comp(t); vmcnt(4); barrier
        stage(lds0, 0);
        asm volatile("s_waitcnt vmcnt(0)" ::: "memory");
        __builtin_amdgcn_s_barrier();

        stage(lds1, 1);
        __builtin_amdgcn_sched_barrier(0);
        comp(lds0, 0);
        asm volatile("s_waitcnt vmcnt(4)" ::: "memory");
        __builtin_amdgcn_s_barrier();

        stage(lds0, 2);
        __builtin_amdgcn_sched_barrier(0);
        comp(lds1, 1);
        asm volatile("s_waitcnt vmcnt(4)" ::: "memory");
        __builtin_amdgcn_s_barrier();

        stage(lds1, 3);
        __builtin_amdgcn_sched_barrier(0);
        comp(lds0, 2);
        asm volatile("s_waitcnt vmcnt(4)" ::: "memory");
        __builtin_amdgcn_s_barrier();

        comp(lds1, 3);
    } else {
        // tail block: exactly 32 rows (100000 % 128 == 32), one half
        stage(lds0, 0);
        asm volatile("s_waitcnt vmcnt(0)" ::: "memory");
        __builtin_amdgcn_s_barrier();
        comp(lds0, 0);
    }
}

extern "C" void kernel_launch(void* const* d_in, const int* in_sizes, int n_in,
                              void* d_out, int out_size, void* d_ws, size_t ws_size,
                              hipStream_t stream) {
    const float* x = (const float*)d_in[0];
    const float* w = (const float*)d_in[1];
    float* y = (float*)d_out;
    unsigned short* wt = (unsigned short*)d_ws;  // 128 KiB of scratch used

    prep_weights<<<256, 256, 0, stream>>>(w, wt);

    dim3 grid((N_NODES + 127) / 128, MCOMP);  // 782 x 16
    linear_mfma<<<grid, 256, 0, stream>>>(x, wt, y);
}